// Round 5
// baseline (349.619 us; speedup 1.0000x reference)
//
#include <hip/hip_runtime.h>
#include <math.h>

// Problem constants
#define NB 4      // batch
#define C  128    // channels (q/k/v/out)
#define CCH 256   // context channels
#define HH 64
#define WW 64
#define NN 4096   // HH*WW
#define HC 32
#define WC 32
#define PP 66     // padded spatial dim for conv input (64 + 2 halo)

typedef unsigned short u16;
typedef unsigned int uint32;
typedef short s16x4 __attribute__((ext_vector_type(4)));    // 4 bf16 (2 VGPR)
typedef short s16x8 __attribute__((ext_vector_type(8)));    // 8 bf16 = MFMA A/B frag
typedef float f32x4 __attribute__((ext_vector_type(4)));    // 16x16 MFMA C/D frag
typedef float f32x16 __attribute__((ext_vector_type(16)));  // 32x32 MFMA C/D frag

// fp32 -> bf16 round-to-nearest-even
__device__ __forceinline__ u16 f2bf(float f) {
    uint32 u = __float_as_uint(f);
    u += 0x7fffu + ((u >> 16) & 1u);
    return (u16)(u >> 16);
}

// ---------------------------------------------------------------------------
// 1) Bilinear 2x upsample, half-pixel centers, clamped edges -> ctx_up f32 [b][cc][n]
// ---------------------------------------------------------------------------
__global__ __launch_bounds__(256) void upsample_kernel(const float* __restrict__ ctx,
                                                       float* __restrict__ out) {
    int idx = blockIdx.x * 256 + threadIdx.x;          // over NB*CCH*NN
    int x = idx & 63, y = (idx >> 6) & 63, bc = idx >> 12;
    float sy = y * 0.5f - 0.25f;
    float sx = x * 0.5f - 0.25f;
    int y0 = (int)floorf(sy), x0 = (int)floorf(sx);
    float wy = sy - (float)y0, wx = sx - (float)x0;
    int y0c = y0 < 0 ? 0 : y0;
    int y1c = (y0 + 1 > HC - 1) ? HC - 1 : y0 + 1;
    int x0c = x0 < 0 ? 0 : x0;
    int x1c = (x0 + 1 > WC - 1) ? WC - 1 : x0 + 1;
    const float* p = ctx + (size_t)bc * (HC * WC);
    float v00 = p[y0c * WC + x0c], v01 = p[y0c * WC + x1c];
    float v10 = p[y1c * WC + x0c], v11 = p[y1c * WC + x1c];
    out[idx] = (1.f - wy) * ((1.f - wx) * v00 + wx * v01)
             +        wy  * ((1.f - wx) * v10 + wx * v11);
}

// ---------------------------------------------------------------------------
// 2) Transpose-cast: in f32 [b][Cin][NN] -> out bf16 [b][NN][Cin]
//    grid (NN/64, Cin/64, NB)
// ---------------------------------------------------------------------------
__global__ __launch_bounds__(256) void tcast(const float* __restrict__ in,
                                             u16* __restrict__ out, int Cin) {
    __shared__ float ls[64 * 65];
    int b = blockIdx.z;
    int ci0 = blockIdx.y * 64;
    int n0 = blockIdx.x * 64;
    int tid = threadIdx.x;
    const float* inb = in + ((size_t)b * Cin + ci0) * NN + n0;
#pragma unroll
    for (int L = 0; L < 4; L++) {
        int fc = tid + L * 256;           // 0..1023
        int nc = fc & 15, ci = fc >> 4;
        float4 v = *(const float4*)(inb + (size_t)ci * NN + nc * 4);
        float* d = &ls[ci * 65 + nc * 4];
        d[0] = v.x; d[1] = v.y; d[2] = v.z; d[3] = v.w;
    }
    __syncthreads();
    u16* ob = out + ((size_t)b * NN + n0) * Cin + ci0;
#pragma unroll
    for (int j = 0; j < 16; j++) {
        int o = tid + j * 256;            // 0..4095
        int ci = o & 63, n = o >> 6;
        ob[(size_t)n * Cin + ci] = f2bf(ls[ci * 65 + n]);
    }
}

// ---------------------------------------------------------------------------
// 3) Cast Wq|Wk|Wv fp32 -> bf16 (contiguous: wq 16384 | wk 32768 | wv 32768)
// ---------------------------------------------------------------------------
__global__ __launch_bounds__(256) void wcast(const float* __restrict__ Wq,
                                             const float* __restrict__ Wk,
                                             const float* __restrict__ Wv,
                                             u16* __restrict__ wbf) {
    int i = blockIdx.x * 256 + threadIdx.x;   // 0..81919
    float v;
    if (i < 16384) v = Wq[i];
    else if (i < 49152) v = Wk[i - 16384];
    else v = Wv[i - 49152];
    wbf[i] = f2bf(v);
}

// ---------------------------------------------------------------------------
// 4) Conv weight prep: Wp fp32 [co][ci][ky][kx] -> wt bf16 [pos][cib][co][ci32]
// ---------------------------------------------------------------------------
__global__ __launch_bounds__(256) void wprep(const float* __restrict__ Wp,
                                             u16* __restrict__ wt) {
    int idx = blockIdx.x * 256 + threadIdx.x;   // 147456
    int ciin = idx & 31;
    int co = (idx >> 5) & 127;
    int cb = (idx >> 12) & 3;
    int pos = idx >> 14;
    int ky = pos / 3, kx = pos - ky * 3;
    int ci = cb * 32 + ciin;
    wt[idx] = f2bf(Wp[((size_t)(co * C + ci) * 3 + ky) * 3 + kx]);
}

// ---------------------------------------------------------------------------
// 5) Zero helpers (ws is poisoned before every call)
// ---------------------------------------------------------------------------
__global__ __launch_bounds__(256) void zero_att(uint4* __restrict__ p) {
    p[blockIdx.x * 256 + threadIdx.x] = make_uint4(0, 0, 0, 0);
}
__global__ __launch_bounds__(256) void zero_acc(uint4* __restrict__ p) {
    p[blockIdx.x * 256 + threadIdx.x] = make_uint4(0, 0, 0, 0);
}

// ---------------------------------------------------------------------------
// 6a) Projection MFMA (transposed out): outT[b][n][128] = bias + X^T W^T
//     D^T[n][co]: A = X^T (m=n), B = W (n-idx=co). Wave: 64n x 128co.
//     grid (16, NB); no LDS, no barriers; W streams from L1/L2.
// ---------------------------------------------------------------------------
__global__ __launch_bounds__(256, 2) void proj_t(const u16* __restrict__ xt,
                                                 const u16* __restrict__ wbf,
                                                 const float* __restrict__ bias,
                                                 u16* __restrict__ outT, int Cin) {
    int b = blockIdx.y;
    int tid = threadIdx.x;
    int w = tid >> 6, lane = tid & 63, l31 = lane & 31, half = lane >> 5;
    int n0 = blockIdx.x * 256 + w * 64;
    const u16* xb = xt + ((size_t)b * NN) * Cin;
    f32x16 acc[2][4];
#pragma unroll
    for (int mt = 0; mt < 2; mt++)
#pragma unroll
        for (int nt = 0; nt < 4; nt++)
#pragma unroll
            for (int i = 0; i < 16; i++) acc[mt][nt][i] = 0.f;
    int nkg = Cin >> 4;
    for (int kg = 0; kg < nkg; kg++) {
        int ko = kg * 16 + half * 8;
        s16x8 a0 = *(const s16x8*)(xb + (size_t)(n0 + l31) * Cin + ko);
        s16x8 a1 = *(const s16x8*)(xb + (size_t)(n0 + 32 + l31) * Cin + ko);
#pragma unroll
        for (int nt = 0; nt < 4; nt++) {
            s16x8 wf = *(const s16x8*)(wbf + (size_t)(nt * 32 + l31) * Cin + ko);
            acc[0][nt] = __builtin_amdgcn_mfma_f32_32x32x16_bf16(a0, wf, acc[0][nt], 0, 0, 0);
            acc[1][nt] = __builtin_amdgcn_mfma_f32_32x32x16_bf16(a1, wf, acc[1][nt], 0, 0, 0);
        }
    }
    u16* ob = outT + (size_t)b * NN * C;
#pragma unroll
    for (int nt = 0; nt < 4; nt++) {
        float bv = bias[nt * 32 + l31];
#pragma unroll
        for (int mt = 0; mt < 2; mt++)
#pragma unroll
            for (int r = 0; r < 16; r++) {
                int n = n0 + mt * 32 + (r & 3) + 8 * (r >> 2) + 4 * half;
                ob[(size_t)n * C + nt * 32 + l31] = f2bf(acc[mt][nt][r] + bv);
            }
    }
}

// ---------------------------------------------------------------------------
// 6b) Projection MFMA (normal out): outN[b][128][n] = bias + W X
//     D[co][n]: A = W (m=co), B = X^T (n-idx=n). Wave: 128co x 64n.
// ---------------------------------------------------------------------------
__global__ __launch_bounds__(256, 2) void proj_v(const u16* __restrict__ xt,
                                                 const u16* __restrict__ wbf,
                                                 const float* __restrict__ bias,
                                                 u16* __restrict__ outN, int Cin) {
    int b = blockIdx.y;
    int tid = threadIdx.x;
    int w = tid >> 6, lane = tid & 63, l31 = lane & 31, half = lane >> 5;
    int n0 = blockIdx.x * 256 + w * 64;
    const u16* xb = xt + ((size_t)b * NN) * Cin;
    f32x16 acc[4][2];
#pragma unroll
    for (int mt = 0; mt < 4; mt++)
#pragma unroll
        for (int nt = 0; nt < 2; nt++)
#pragma unroll
            for (int i = 0; i < 16; i++) acc[mt][nt][i] = 0.f;
    int nkg = Cin >> 4;
    for (int kg = 0; kg < nkg; kg++) {
        int ko = kg * 16 + half * 8;
        s16x8 b0 = *(const s16x8*)(xb + (size_t)(n0 + l31) * Cin + ko);
        s16x8 b1 = *(const s16x8*)(xb + (size_t)(n0 + 32 + l31) * Cin + ko);
#pragma unroll
        for (int mt = 0; mt < 4; mt++) {
            s16x8 wf = *(const s16x8*)(wbf + (size_t)(mt * 32 + l31) * Cin + ko);
            acc[mt][0] = __builtin_amdgcn_mfma_f32_32x32x16_bf16(wf, b0, acc[mt][0], 0, 0, 0);
            acc[mt][1] = __builtin_amdgcn_mfma_f32_32x32x16_bf16(wf, b1, acc[mt][1], 0, 0, 0);
        }
    }
    u16* ob = outN + (size_t)b * C * NN;
#pragma unroll
    for (int mt = 0; mt < 4; mt++)
#pragma unroll
        for (int r = 0; r < 16; r++) {
            int co = mt * 32 + (r & 3) + 8 * (r >> 2) + 4 * half;
            float bv = bias[co];
#pragma unroll
            for (int nt = 0; nt < 2; nt++)
                ob[(size_t)co * NN + n0 + nt * 32 + l31] = f2bf(acc[mt][nt][r] + bv);
        }
}

// ---------------------------------------------------------------------------
// 7) Flash attention v3: streaming fragments from L1/L2, NO barriers.
//    S^T = K·Q (rows=key, cols=q) -> packed b64 P-writes into wave-private LDS
//    -> PV as O^T = V·P^T (A=V, B=P^T). Split-K x8, fp32 atomic accumulation.
//    Block: 4 waves x 64q = 256q. Grid 512 = 4b x 16 qblk x 8 split.
//    acc layout [b][c][n] (coalesced atomic segments); lacc [b][n].
// ---------------------------------------------------------------------------
__global__ __launch_bounds__(256, 2) void flash_mfma(const u16* __restrict__ qt_p,
                                                     const u16* __restrict__ kt_p,
                                                     const u16* __restrict__ vt_p,
                                                     float* __restrict__ acc,
                                                     float* __restrict__ lacc) {
    __shared__ u16 ps[4][2][32 * 68];   // [wave][qt][q][m] stride 68, 34.8 KB

    int ib = blockIdx.x;
    int b = (ib & 7) >> 1;                       // batch -> XCD pair
    int rest = ((ib >> 3) << 1) | (ib & 1);      // 0..127
    int qblk = rest >> 3;                        // 0..15
    int split = rest & 7;                        // 0..7
    int tid = threadIdx.x;
    int w = tid >> 6, lane = tid & 63, l31 = lane & 31, half = lane >> 5;
    int n0 = qblk * 256 + w * 64;

    const u16* qtb = qt_p + (size_t)b * NN * C;
    const u16* ktb = kt_p + (size_t)b * NN * C;
    const u16* vtb = vt_p + (size_t)b * C * NN;

    // Q fragments in registers, reused across all key iterations
    s16x8 qf[2][8];
#pragma unroll
    for (int qt2 = 0; qt2 < 2; qt2++)
#pragma unroll
        for (int kg = 0; kg < 8; kg++)
            qf[qt2][kg] = *(const s16x8*)(qtb + (size_t)(n0 + qt2 * 32 + l31) * C + kg * 16 + half * 8);

    f32x16 oacc[4][2];   // [c-tile][qt]
#pragma unroll
    for (int mt = 0; mt < 4; mt++)
#pragma unroll
        for (int qt2 = 0; qt2 < 2; qt2++)
#pragma unroll
            for (int i = 0; i < 16; i++) oacc[mt][qt2][i] = 0.f;
    float lsum[2] = {0.f, 0.f};

    int m_base = split * 512;
    for (int it = 0; it < 8; it++) {
        int m0 = m_base + it * 64;
        // ---- S^T tiles + exp + packed P write (wave-private, no barrier) ----
#pragma unroll
        for (int qt2 = 0; qt2 < 2; qt2++) {
#pragma unroll
            for (int kmt = 0; kmt < 2; kmt++) {
                f32x16 s;
#pragma unroll
                for (int i = 0; i < 16; i++) s[i] = 0.f;
#pragma unroll
                for (int kg = 0; kg < 8; kg++) {
                    s16x8 kf = *(const s16x8*)(ktb + (size_t)(m0 + kmt * 32 + l31) * C + kg * 16 + half * 8);
                    s = __builtin_amdgcn_mfma_f32_32x32x16_bf16(kf, qf[qt2][kg], s, 0, 0, 0);
                }
#pragma unroll
                for (int rg = 0; rg < 4; rg++) {
                    float e0 = __expf(s[rg * 4 + 0]);
                    float e1 = __expf(s[rg * 4 + 1]);
                    float e2 = __expf(s[rg * 4 + 2]);
                    float e3 = __expf(s[rg * 4 + 3]);
                    lsum[qt2] += e0 + e1 + e2 + e3;
                    // truncate-to-bf16 pack (systematic part cancels in O/l)
                    uint32 lo = __builtin_amdgcn_perm(__float_as_uint(e1), __float_as_uint(e0), 0x07060302u);
                    uint32 hi = __builtin_amdgcn_perm(__float_as_uint(e3), __float_as_uint(e2), 0x07060302u);
                    uint2 pk = make_uint2(lo, hi);
                    *(uint2*)&ps[w][qt2][l31 * 68 + kmt * 32 + rg * 8 + half * 4] = pk;
                }
            }
        }
        // ---- PV: O^T += V·P^T ----
#pragma unroll
        for (int kg = 0; kg < 4; kg++) {
            s16x8 pf0, pf1;
            {
                const u16* p0 = &ps[w][0][l31 * 68 + kg * 16 + half * 8];
                *(s16x4*)&pf0 = *(const s16x4*)p0;
                *((s16x4*)&pf0 + 1) = *(const s16x4*)(p0 + 4);
                const u16* p1 = &ps[w][1][l31 * 68 + kg * 16 + half * 8];
                *(s16x4*)&pf1 = *(const s16x4*)p1;
                *((s16x4*)&pf1 + 1) = *(const s16x4*)(p1 + 4);
            }
#pragma unroll
            for (int mt = 0; mt < 4; mt++) {
                s16x8 vf = *(const s16x8*)(vtb + (size_t)(mt * 32 + l31) * NN + m0 + kg * 16 + half * 8);
                oacc[mt][0] = __builtin_amdgcn_mfma_f32_32x32x16_bf16(vf, pf0, oacc[mt][0], 0, 0, 0);
                oacc[mt][1] = __builtin_amdgcn_mfma_f32_32x32x16_bf16(vf, pf1, oacc[mt][1], 0, 0, 0);
            }
        }
    }

    // ---- epilogue: lsum across halves; coalesced atomic adds ----
    float* lb = lacc + (size_t)b * NN;
#pragma unroll
    for (int qt2 = 0; qt2 < 2; qt2++) {
        float s = lsum[qt2] + __shfl_xor(lsum[qt2], 32);
        if (half == 0) atomicAdd(&lb[n0 + qt2 * 32 + l31], s);
    }
    float* ab = acc + (size_t)b * C * NN;
#pragma unroll
    for (int mt = 0; mt < 4; mt++)
#pragma unroll
        for (int r = 0; r < 16; r++) {
            int c = mt * 32 + (r & 3) + 8 * (r >> 2) + 4 * half;
#pragma unroll
            for (int qt2 = 0; qt2 < 2; qt2++)
                atomicAdd(&ab[(size_t)c * NN + n0 + qt2 * 32 + l31], oacc[mt][qt2][r]);
        }
}

// ---------------------------------------------------------------------------
// 8) Combine: att_t[b][y+1][x+1][c] = bf16( acc[b][c][n] / lacc[b][n] )
//    LDS transpose so both read and write are coalesced. grid (64, NB).
// ---------------------------------------------------------------------------
__global__ __launch_bounds__(256) void flash_combine(const float* __restrict__ acc,
                                                     const float* __restrict__ lacc,
                                                     u16* __restrict__ att_t) {
    __shared__ u16 ts[128 * 66];
    __shared__ float linv[64];
    int b = blockIdx.y;
    int nt = blockIdx.x;            // 64-pixel tile == image row y
    int n0 = nt * 64;
    int tid = threadIdx.x;
    if (tid < 64) linv[tid] = 1.0f / lacc[(size_t)b * NN + n0 + tid];
    __syncthreads();
    const float* ab = acc + (size_t)b * C * NN + n0;
#pragma unroll
    for (int j = 0; j < 32; j++) {
        int e = tid + j * 256;      // 8192
        int n = e & 63, c = e >> 6;
        ts[c * 66 + n] = f2bf(ab[(size_t)c * NN + n] * linv[n]);
    }
    __syncthreads();
    u16* ob = att_t + ((size_t)b * PP * PP + (size_t)(nt + 1) * PP + 1) * C;
#pragma unroll
    for (int j = 0; j < 32; j++) {
        int o = tid + j * 256;      // 8192
        int c = o & 127, n = o >> 7;
        ob[(size_t)n * C + c] = ts[c * 66 + n];
    }
}

// ---------------------------------------------------------------------------
// 9) Implicit-GEMM MFMA conv3x3 + residual (unchanged from round 3).
// ---------------------------------------------------------------------------
__global__ __launch_bounds__(256) void conv3x3_mfma(const u16* __restrict__ att_t,
                                                    const u16* __restrict__ wt,
                                                    const float* __restrict__ bp,
                                                    const float* __restrict__ sr,
                                                    const float* __restrict__ gamma,
                                                    float* __restrict__ out) {
    __shared__ u16 in_s[2][4 * 204 * 8];
    int ib = blockIdx.x;
    int b = (ib & 7) >> 1;
    int y = ((ib >> 3) << 1) | (ib & 1);
    int tid = threadIdx.x;
    int w = tid >> 6, lane = tid & 63, l = tid & 15, quad = (tid >> 4) & 3;
    const u16* ab = att_t + (size_t)b * (PP * PP * C);

    auto stage = [&](int cib, int bufi) {
        u16* base = &in_s[bufi][w * 204 * 8];
        const u16* gsrc = ab + cib * 32 + w * 8;
#pragma unroll
        for (int t = 0; t < 4; t++) {
            int rem = t * 64 + lane;
            int r = rem / 68, xp = rem - r * 68;
            if (t < 3 || lane < 12)
                __builtin_amdgcn_global_load_lds(
                    (const __attribute__((address_space(1))) void*)(gsrc + (size_t)((y + r) * PP + xp) * C),
                    (__attribute__((address_space(3))) void*)(base + (size_t)t * 64 * 8), 16, 0, 0);
        }
    };

    f32x4 acc[2][4];
#pragma unroll
    for (int cf = 0; cf < 2; cf++)
#pragma unroll
        for (int nf = 0; nf < 4; nf++) acc[cf][nf] = (f32x4){0.f, 0.f, 0.f, 0.f};
    int cow = w * 32;

    stage(0, 0);
    __syncthreads();
#pragma unroll
    for (int cib = 0; cib < 4; cib++) {
        if (cib < 3) stage(cib + 1, (cib + 1) & 1);
        const u16* bufc = &in_s[cib & 1][0];
#pragma unroll
        for (int ky = 0; ky < 3; ky++)
#pragma unroll
            for (int kx = 0; kx < 3; kx++) {
                int pos = ky * 3 + kx;
                s16x8 wf[2];
#pragma unroll
                for (int cf = 0; cf < 2; cf++)
                    wf[cf] = *(const s16x8*)&wt[((size_t)(pos * 4 + cib) * C + cow + cf * 16 + l) * 32 + quad * 8];
#pragma unroll
                for (int nf = 0; nf < 4; nf++) {
                    s16x8 inf = *(const s16x8*)&bufc[(quad * 204 + ky * 68 + nf * 16 + l + kx) * 8];
                    acc[0][nf] = __builtin_amdgcn_mfma_f32_16x16x32_bf16(wf[0], inf, acc[0][nf], 0, 0, 0);
                    acc[1][nf] = __builtin_amdgcn_mfma_f32_16x16x32_bf16(wf[1], inf, acc[1][nf], 0, 0, 0);
                }
            }
        __syncthreads();
    }

    float g = gamma[0];
    float* ob = out + (size_t)b * C * NN;
    const float* sb = sr + (size_t)b * C * NN;
#pragma unroll
    for (int cf = 0; cf < 2; cf++)
#pragma unroll
        for (int r = 0; r < 4; r++) {
            int co = cow + cf * 16 + quad * 4 + r;
            float bias = bp[co];
#pragma unroll
            for (int nf = 0; nf < 4; nf++) {
                size_t oo = (size_t)co * NN + y * 64 + nf * 16 + l;
                ob[oo] = sb[oo] + g * (acc[cf][nf][r] + bias);
            }
        }
}

// ---------------------------------------------------------------------------
extern "C" void kernel_launch(void* const* d_in, const int* in_sizes, int n_in,
                              void* d_out, int out_size, void* d_ws, size_t ws_size,
                              hipStream_t stream) {
    const float* sr    = (const float*)d_in[0];
    const float* ctx   = (const float*)d_in[1];
    const float* Wq    = (const float*)d_in[2];
    const float* bq    = (const float*)d_in[3];
    const float* Wk    = (const float*)d_in[4];
    const float* bk    = (const float*)d_in[5];
    const float* Wv    = (const float*)d_in[6];
    const float* bv    = (const float*)d_in[7];
    const float* Wp    = (const float*)d_in[8];
    const float* bp    = (const float*)d_in[9];
    const float* gamma = (const float*)d_in[10];
    float* out = (float*)d_out;

    // ws layout (bytes), ~47 MB total:
    //   att_t bf16 [B][66][66][C]   @0       (4,460,544)
    //   ctx_up f32 [B][CCH][N]      @5 MB    (16 MB)  -- dead after tcast(ctx)
    //   acc f32 [B][C][N] + lacc    @5 MB    (8,454,144) overlays ctx_up
    //   ctx_t bf16 [B][N][CCH]      @22 MB   (8 MB)
    //   sr_t bf16 [B][N][C]         @30 MB   (4 MB)
    //   q_t bf16 [B][N][C]          @34 MB   (4 MB)
    //   k_t bf16 [B][N][C]          @38 MB   (4 MB)
    //   v bf16 [B][C][N]            @42 MB   (4 MB)
    //   wt bf16 (conv)              @46 MB   (294,912)
    //   w_bf bf16 (q|k|v)           @46.5 MB (163,840)
    char* wsb = (char*)d_ws;
    u16*   att_t  = (u16*)wsb;
    float* ctx_up = (float*)(wsb + (5u << 20));
    float* acc    = (float*)(wsb + (5u << 20));
    float* lacc   = acc + (size_t)NB * C * NN;
    u16*   ctx_t  = (u16*)(wsb + (22u << 20));
    u16*   sr_t   = (u16*)(wsb + (30u << 20));
    u16*   q_t    = (u16*)(wsb + (34u << 20));
    u16*   k_t    = (u16*)(wsb + (38u << 20));
    u16*   v_bf   = (u16*)(wsb + (42u << 20));
    u16*   wt     = (u16*)(wsb + (46u << 20));
    u16*   w_bf   = (u16*)(wsb + (46u << 20) + (512u << 10));
    u16*   wq_bf  = w_bf;
    u16*   wk_bf  = w_bf + 16384;
    u16*   wv_bf  = w_bf + 49152;

    upsample_kernel<<<dim3(16384), 256, 0, stream>>>(ctx, ctx_up);
    tcast<<<dim3(64, 4, NB), 256, 0, stream>>>(ctx_up, ctx_t, CCH);
    tcast<<<dim3(64, 2, NB), 256, 0, stream>>>(sr, sr_t, C);
    wcast<<<dim3(320), 256, 0, stream>>>(Wq, Wk, Wv, w_bf);
    wprep<<<dim3(576), 256, 0, stream>>>(Wp, wt);
    zero_att<<<dim3(1089), 256, 0, stream>>>((uint4*)att_t);
    zero_acc<<<dim3(2064), 256, 0, stream>>>((uint4*)acc);   // after ctx_up dead
    proj_t<<<dim3(16, NB), 256, 0, stream>>>(sr_t, wq_bf, bq, q_t, C);
    proj_t<<<dim3(16, NB), 256, 0, stream>>>(ctx_t, wk_bf, bk, k_t, CCH);
    proj_v<<<dim3(16, NB), 256, 0, stream>>>(ctx_t, wv_bf, bv, v_bf, CCH);
    flash_mfma<<<dim3(512), 256, 0, stream>>>(q_t, k_t, v_bf, acc, lacc);
    flash_combine<<<dim3(64, NB), 256, 0, stream>>>(acc, lacc, att_t);
    conv3x3_mfma<<<dim3(256), 256, 0, stream>>>(att_t, wt, bp, sr, gamma, out);
}

// Round 6
// 222.513 us; speedup vs baseline: 1.5712x; 1.5712x over previous
//
#include <hip/hip_runtime.h>
#include <math.h>

// Problem constants
#define NB 4      // batch
#define C  128    // channels (q/k/v/out)
#define CCH 256   // context channels
#define HH 64
#define WW 64
#define NN 4096   // HH*WW
#define HC 32
#define WC 32
#define PP 66     // padded spatial dim for conv input (64 + 2 halo)

typedef unsigned short u16;
typedef unsigned int uint32;
typedef short s16x8 __attribute__((ext_vector_type(8)));    // 8 bf16 = MFMA A/B frag
typedef float f32x4 __attribute__((ext_vector_type(4)));    // 16x16 MFMA C/D frag
typedef float f32x16 __attribute__((ext_vector_type(16)));  // 32x32 MFMA C/D frag

// fp32 -> bf16 round-to-nearest-even
__device__ __forceinline__ u16 f2bf(float f) {
    uint32 u = __float_as_uint(f);
    u += 0x7fffu + ((u >> 16) & 1u);
    return (u16)(u >> 16);
}

// ---------------------------------------------------------------------------
// 1) Fused bilinear 2x upsample + transpose-cast: ctx f32 [b][cc][32][32]
//    -> ctx_t bf16 [b][n][cc].  Block = (y row, cc-half 128, b). LDS-staged.
// ---------------------------------------------------------------------------
__global__ __launch_bounds__(256) void upsample_t(const float* __restrict__ ctx,
                                                  u16* __restrict__ ctx_t) {
    __shared__ float ls[2][32][130];   // [src row][x][cc] pad-130, 33.3 KB
    int y = blockIdx.x;        // 0..63
    int cch = blockIdx.y;      // 0..1
    int b = blockIdx.z;
    float sy = y * 0.5f - 0.25f;
    int y0 = (int)floorf(sy);
    float wy = sy - (float)y0;
    int y0c = y0 < 0 ? 0 : y0;
    int y1c = (y0 + 1 > HC - 1) ? HC - 1 : y0 + 1;
    int tid = threadIdx.x;
#pragma unroll
    for (int t = 0; t < 4; t++) {
        int CI = t * 256 + tid;            // 0..1023
        int cc = CI >> 3, xq = CI & 7;
        const float* s = ctx + (size_t)(b * CCH + cch * 128 + cc) * (HC * WC);
        float4 v0 = *(const float4*)(s + y0c * WC + xq * 4);
        float4 v1 = *(const float4*)(s + y1c * WC + xq * 4);
        ls[0][xq * 4 + 0][cc] = v0.x; ls[0][xq * 4 + 1][cc] = v0.y;
        ls[0][xq * 4 + 2][cc] = v0.z; ls[0][xq * 4 + 3][cc] = v0.w;
        ls[1][xq * 4 + 0][cc] = v1.x; ls[1][xq * 4 + 1][cc] = v1.y;
        ls[1][xq * 4 + 2][cc] = v1.z; ls[1][xq * 4 + 3][cc] = v1.w;
    }
    __syncthreads();
    int occ = tid & 127, xh = tid >> 7;
    u16* ob = ctx_t + ((size_t)b * NN + (size_t)y * 64) * CCH + cch * 128 + occ;
    float wy1 = 1.f - wy;
#pragma unroll
    for (int xi = 0; xi < 32; xi++) {
        int x = xi * 2 + xh;
        float sx = x * 0.5f - 0.25f;
        int x0 = (int)floorf(sx);
        float wx = sx - (float)x0;
        int x0c = x0 < 0 ? 0 : x0;
        int x1c = (x0 + 1 > WC - 1) ? WC - 1 : x0 + 1;
        float v00 = ls[0][x0c][occ], v01 = ls[0][x1c][occ];
        float v10 = ls[1][x0c][occ], v11 = ls[1][x1c][occ];
        float val = wy1 * ((1.f - wx) * v00 + wx * v01)
                  + wy  * ((1.f - wx) * v10 + wx * v11);
        ob[(size_t)x * CCH] = f2bf(val);
    }
}

// ---------------------------------------------------------------------------
// 2) Transpose-cast: sr f32 [b][C][NN] -> sr_t bf16 [b][NN][C]
// ---------------------------------------------------------------------------
__global__ __launch_bounds__(256) void tcast(const float* __restrict__ in,
                                             u16* __restrict__ out, int Cin) {
    __shared__ float ls[64 * 65];
    int b = blockIdx.z;
    int ci0 = blockIdx.y * 64;
    int n0 = blockIdx.x * 64;
    int tid = threadIdx.x;
    const float* inb = in + ((size_t)b * Cin + ci0) * NN + n0;
#pragma unroll
    for (int L = 0; L < 4; L++) {
        int fc = tid + L * 256;
        int nc = fc & 15, ci = fc >> 4;
        float4 v = *(const float4*)(inb + (size_t)ci * NN + nc * 4);
        float* d = &ls[ci * 65 + nc * 4];
        d[0] = v.x; d[1] = v.y; d[2] = v.z; d[3] = v.w;
    }
    __syncthreads();
    u16* ob = out + ((size_t)b * NN + n0) * Cin + ci0;
#pragma unroll
    for (int j = 0; j < 16; j++) {
        int o = tid + j * 256;
        int ci = o & 63, n = o >> 6;
        ob[(size_t)n * Cin + ci] = f2bf(ls[ci * 65 + n]);
    }
}

// ---------------------------------------------------------------------------
// 3) Weight prep (fused): Wq|Wk|Wv cast -> w_bf; Wp -> wt [pos][cib][co][ci32]
// ---------------------------------------------------------------------------
__global__ __launch_bounds__(256) void wprep_all(const float* __restrict__ Wq,
                                                 const float* __restrict__ Wk,
                                                 const float* __restrict__ Wv,
                                                 const float* __restrict__ Wp,
                                                 u16* __restrict__ wbf,
                                                 u16* __restrict__ wt) {
    int i = blockIdx.x * 256 + threadIdx.x;   // 0..229375
    if (i < 81920) {
        float v;
        if (i < 16384) v = Wq[i];
        else if (i < 49152) v = Wk[i - 16384];
        else v = Wv[i - 49152];
        wbf[i] = f2bf(v);
    } else {
        int idx = i - 81920;                  // 0..147455
        int ciin = idx & 31;
        int co = (idx >> 5) & 127;
        int cb = (idx >> 12) & 3;
        int pos = idx >> 14;
        int ky = pos / 3, kx = pos - ky * 3;
        int ci = cb * 32 + ciin;
        wt[idx] = f2bf(Wp[((size_t)(co * C + ci) * 3 + ky) * 3 + kx]);
    }
}

// ---------------------------------------------------------------------------
// 4) Zero att_t + acc + lacc in one kernel (ws poisoned every call)
// ---------------------------------------------------------------------------
__global__ __launch_bounds__(256) void zero_all(uint4* __restrict__ att,
                                                uint4* __restrict__ acc) {
    int i = blockIdx.x * 256 + threadIdx.x;   // 0..807167
    if (i < 278784) att[i] = make_uint4(0, 0, 0, 0);
    else acc[i - 278784] = make_uint4(0, 0, 0, 0);
}

// ---------------------------------------------------------------------------
// 5) Fused projection GEMM (q/k/v by blockIdx.z), LDS-staged both operands.
//    Block 256 thr: 128 n x 128 co, BK=64. Wave w -> (xh=w>>1, wh=w&1).
//    z=0: q = Wq sr_t  -> q_t [n][C]   (T-mode)
//    z=1: k = Wk ctx_t -> k_t [n][C]   (T-mode)
//    z=2: v = Wv ctx_t -> v   [C][n]   (V-mode, swapped operands)
// ---------------------------------------------------------------------------
__global__ __launch_bounds__(256) void proj_all(const u16* __restrict__ sr_t,
                                                const u16* __restrict__ ctx_t,
                                                const u16* __restrict__ wbf,
                                                const float* __restrict__ bq,
                                                const float* __restrict__ bk,
                                                const float* __restrict__ bv,
                                                u16* __restrict__ q_t,
                                                u16* __restrict__ k_t,
                                                u16* __restrict__ v_bf) {
    __shared__ u16 xs[128 * 64];   // [n-row][ci] chunk-swizzled, 16 KB
    __shared__ u16 wsm[128 * 64];  // [co][ci]    chunk-swizzled, 16 KB
    int z = blockIdx.z;
    int b = blockIdx.y;
    int n0 = blockIdx.x * 128;
    int Cin = (z == 0) ? C : CCH;
    const u16* xb = (z == 0 ? sr_t : ctx_t) + (size_t)b * NN * Cin;
    const u16* wb = wbf + (z == 0 ? 0 : (z == 1 ? 16384 : 49152));
    const float* bias = (z == 0) ? bq : (z == 1 ? bk : bv);
    bool vmode = (z == 2);

    int tid = threadIdx.x;
    int w = tid >> 6, lane = tid & 63, l31 = lane & 31, half = lane >> 5;
    int xh = w >> 1, wh = w & 1;

    f32x16 acc[2][2];
#pragma unroll
    for (int xt = 0; xt < 2; xt++)
#pragma unroll
        for (int wt2 = 0; wt2 < 2; wt2++)
#pragma unroll
            for (int i = 0; i < 16; i++) acc[xt][wt2][i] = 0.f;

    int nchunks = Cin >> 6;
    for (int c0i = 0; c0i < nchunks; c0i++) {
        int c0 = c0i * 64;
        __syncthreads();   // previous chunk's reads done
        // stage xs: 128 rows x 8 chunks of 16B, swizzle chunk ^ (row&7)
#pragma unroll
        for (int t = 0; t < 4; t++) {
            int CI = t * 256 + tid;
            int row = CI >> 3, sl = CI & 7;
            int lc = sl ^ (row & 7);
            __builtin_amdgcn_global_load_lds(
                (const __attribute__((address_space(1))) void*)(xb + (size_t)(n0 + row) * Cin + c0 + lc * 8),
                (__attribute__((address_space(3))) void*)&xs[(size_t)CI * 8], 16, 0, 0);
        }
#pragma unroll
        for (int t = 0; t < 4; t++) {
            int CI = t * 256 + tid;
            int co = CI >> 3, sl = CI & 7;
            int lc = sl ^ (co & 7);
            __builtin_amdgcn_global_load_lds(
                (const __attribute__((address_space(1))) void*)(wb + (size_t)co * Cin + c0 + lc * 8),
                (__attribute__((address_space(3))) void*)&wsm[(size_t)CI * 8], 16, 0, 0);
        }
        __syncthreads();   // staging complete
#pragma unroll
        for (int kg = 0; kg < 4; kg++) {
            int pc = ((kg * 2 + half) ^ (l31 & 7)) * 8;
            s16x8 xf[2], wf2[2];
#pragma unroll
            for (int xt = 0; xt < 2; xt++)
                xf[xt] = *(const s16x8*)&xs[(xh * 64 + xt * 32 + l31) * 64 + pc];
#pragma unroll
            for (int wt2 = 0; wt2 < 2; wt2++)
                wf2[wt2] = *(const s16x8*)&wsm[(wh * 64 + wt2 * 32 + l31) * 64 + pc];
#pragma unroll
            for (int xt = 0; xt < 2; xt++)
#pragma unroll
                for (int wt2 = 0; wt2 < 2; wt2++) {
                    if (vmode)
                        acc[xt][wt2] = __builtin_amdgcn_mfma_f32_32x32x16_bf16(wf2[wt2], xf[xt], acc[xt][wt2], 0, 0, 0);
                    else
                        acc[xt][wt2] = __builtin_amdgcn_mfma_f32_32x32x16_bf16(xf[xt], wf2[wt2], acc[xt][wt2], 0, 0, 0);
                }
        }
    }

    if (!vmode) {
        u16* ot = (z == 0 ? q_t : k_t) + (size_t)b * NN * C;
        float bv2[2];
#pragma unroll
        for (int wt2 = 0; wt2 < 2; wt2++) bv2[wt2] = bias[wh * 64 + wt2 * 32 + l31];
#pragma unroll
        for (int xt = 0; xt < 2; xt++)
#pragma unroll
            for (int r = 0; r < 16; r++) {
                int n = n0 + xh * 64 + xt * 32 + (r & 3) + 8 * (r >> 2) + 4 * half;
#pragma unroll
                for (int wt2 = 0; wt2 < 2; wt2++)
                    ot[(size_t)n * C + wh * 64 + wt2 * 32 + l31] = f2bf(acc[xt][wt2][r] + bv2[wt2]);
            }
    } else {
        u16* ov = v_bf + (size_t)b * C * NN;
#pragma unroll
        for (int wt2 = 0; wt2 < 2; wt2++)
#pragma unroll
            for (int r = 0; r < 16; r++) {
                int co = wh * 64 + wt2 * 32 + (r & 3) + 8 * (r >> 2) + 4 * half;
                float bvv = bias[co];
#pragma unroll
                for (int xt = 0; xt < 2; xt++) {
                    int n = n0 + xh * 64 + xt * 32 + l31;
                    ov[(size_t)co * NN + n] = f2bf(acc[xt][wt2][r] + bvv);
                }
            }
    }
}

// ---------------------------------------------------------------------------
// 6) Flash attention v6: r4's staged 2-barrier skeleton + S^T orientation
//    (packed b64 P-writes) + coalesced [b][c][n] atomic epilogue.
//    Block 256 thr = 4 waves x 32q = 128 q. Split-K x8 (512 keys/block).
//    Grid 1024 = 4b x 32 qtile x 8 split. LDS 51.2 KB.
// ---------------------------------------------------------------------------
__global__ __launch_bounds__(256) void flash_mfma(const u16* __restrict__ qt_p,
                                                  const u16* __restrict__ kt_p,
                                                  const u16* __restrict__ vt_p,
                                                  float* __restrict__ acc,
                                                  float* __restrict__ lacc) {
    __shared__ u16 ks[64 * 128];     // [key][ch]   chunk-XOR16 swizzled, 16 KB
    __shared__ u16 vs[128 * 64];     // [ch][key]   chunk-XOR8 swizzled,  16 KB
    __shared__ u16 ps[4][32 * 72];   // per-wave P [q][m] pad 72, 18.4 KB

    int ib = blockIdx.x;
    int b = (ib & 7) >> 1;                       // batch -> XCD pair
    int rest = ((ib >> 3) << 1) | (ib & 1);      // 0..255
    int qtile = rest >> 3;                       // 0..31
    int split = rest & 7;                        // 0..7
    int n0 = qtile * 128;
    int tid = threadIdx.x;
    int w = tid >> 6, lane = tid & 63, l31 = lane & 31, half = lane >> 5;

    const u16* qtb = qt_p + (size_t)b * NN * C;
    const u16* ktb = kt_p + (size_t)b * NN * C;
    const u16* vtb = vt_p + (size_t)b * C * NN;

    auto stageK = [&](int m0) {
#pragma unroll
        for (int t = 0; t < 4; t++) {
            int CI = (w * 4 + t) * 64 + lane;                 // 0..1023
            int r = CI >> 4;                                  // key row
            int lc = (CI & 15) ^ (r & 15);
            __builtin_amdgcn_global_load_lds(
                (const __attribute__((address_space(1))) void*)(ktb + (size_t)(m0 + r) * C + lc * 8),
                (__attribute__((address_space(3))) void*)&ks[(w * 4 + t) * 512], 16, 0, 0);
        }
    };
    auto stageV = [&](int m0) {
#pragma unroll
        for (int t = 0; t < 4; t++) {
            int CI = (w * 4 + t) * 64 + lane;
            int c = CI >> 3;                                  // channel row
            int lc = (CI & 7) ^ (c & 7);
            __builtin_amdgcn_global_load_lds(
                (const __attribute__((address_space(1))) void*)(vtb + (size_t)c * NN + m0 + lc * 8),
                (__attribute__((address_space(3))) void*)&vs[(w * 4 + t) * 512], 16, 0, 0);
        }
    };

    // Q A-fragments in registers (reused all iterations): 32 q per wave
    int qrow = n0 + w * 32 + l31;
    s16x8 qf[8];
#pragma unroll
    for (int kg = 0; kg < 8; kg++)
        qf[kg] = *(const s16x8*)(qtb + (size_t)qrow * C + kg * 16 + half * 8);

    int m_base = split * 512;
    stageK(m_base);
    __syncthreads();

    f32x16 oacc[4];
#pragma unroll
    for (int mt = 0; mt < 4; mt++)
#pragma unroll
        for (int i = 0; i < 16; i++) oacc[mt][i] = 0.f;
    float lsum = 0.f;

    for (int it = 0; it < 8; it++) {
        int m0 = m_base + it * 64;
        stageV(m0);                               // async, drains at barrier 1

        // ---- S^T = K·Q : rows m (2 tiles of 32), cols q (32) ----
        f32x16 st[2];
#pragma unroll
        for (int kmt = 0; kmt < 2; kmt++)
#pragma unroll
            for (int i = 0; i < 16; i++) st[kmt][i] = 0.f;
#pragma unroll
        for (int kg = 0; kg < 8; kg++) {
            int pc = ((kg * 2 + half) ^ (l31 & 15)) * 8;
#pragma unroll
            for (int kmt = 0; kmt < 2; kmt++) {
                s16x8 kf = *(const s16x8*)&ks[(kmt * 32 + l31) * 128 + pc];
                st[kmt] = __builtin_amdgcn_mfma_f32_32x32x16_bf16(kf, qf[kg], st[kmt], 0, 0, 0);
            }
        }
        __syncthreads();                          // V staged; all waves done with ks
        if (it < 7) stageK(m0 + 64);              // async, drains at barrier 2

        // ---- P = exp(S^T): packed b64 writes into wave-private ps[q][m] ----
#pragma unroll
        for (int kmt = 0; kmt < 2; kmt++)
#pragma unroll
            for (int rg = 0; rg < 4; rg++) {
                float e0 = __expf(st[kmt][rg * 4 + 0]);
                float e1 = __expf(st[kmt][rg * 4 + 1]);
                float e2 = __expf(st[kmt][rg * 4 + 2]);
                float e3 = __expf(st[kmt][rg * 4 + 3]);
                lsum += e0 + e1 + e2 + e3;
                uint32 lo = __builtin_amdgcn_perm(__float_as_uint(e1), __float_as_uint(e0), 0x07060302u);
                uint32 hi = __builtin_amdgcn_perm(__float_as_uint(e3), __float_as_uint(e2), 0x07060302u);
                *(uint2*)&ps[w][l31 * 72 + kmt * 32 + rg * 8 + half * 4] = make_uint2(lo, hi);
            }

        // ---- PV: O^T = V·P^T (rows c, cols q) ----
#pragma unroll
        for (int kg = 0; kg < 4; kg++) {
            s16x8 pf = *(const s16x8*)&ps[w][l31 * 72 + kg * 16 + half * 8];
            int pc = ((kg * 2 + half) ^ (l31 & 7)) * 8;
#pragma unroll
            for (int mt = 0; mt < 4; mt++) {
                s16x8 vf = *(const s16x8*)&vs[(mt * 32 + l31) * 64 + pc];
                oacc[mt] = __builtin_amdgcn_mfma_f32_32x32x16_bf16(vf, pf, oacc[mt], 0, 0, 0);
            }
        }
        __syncthreads();                          // K(it+1) staged; all done with vs
    }

    // ---- epilogue: combine halves of lsum; coalesced atomic adds ----
    float lt = lsum + __shfl_xor(lsum, 32);
    if (half == 0) atomicAdd(&lacc[(size_t)b * NN + qrow], lt);
    float* ab = acc + (size_t)b * C * NN;
#pragma unroll
    for (int mt = 0; mt < 4; mt++)
#pragma unroll
        for (int r = 0; r < 16; r++) {
            int c = mt * 32 + (r & 3) + 8 * (r >> 2) + 4 * half;
            atomicAdd(&ab[(size_t)c * NN + n0 + w * 32 + l31], oacc[mt][r]);
        }
}

// ---------------------------------------------------------------------------
// 7) Combine: att_t[b][y+1][x+1][c] = bf16( acc[b][c][n] / lacc[b][n] )
// ---------------------------------------------------------------------------
__global__ __launch_bounds__(256) void flash_combine(const float* __restrict__ acc,
                                                     const float* __restrict__ lacc,
                                                     u16* __restrict__ att_t) {
    __shared__ u16 ts[128 * 66];
    __shared__ float linv[64];
    int b = blockIdx.y;
    int nt = blockIdx.x;            // image row y
    int n0 = nt * 64;
    int tid = threadIdx.x;
    if (tid < 64) linv[tid] = 1.0f / lacc[(size_t)b * NN + n0 + tid];
    __syncthreads();
    const float* ab = acc + (size_t)b * C * NN + n0;
#pragma unroll
    for (int j = 0; j < 32; j++) {
        int e = tid + j * 256;
        int n = e & 63, c = e >> 6;
        ts[c * 66 + n] = f2bf(ab[(size_t)c * NN + n] * linv[n]);
    }
    __syncthreads();
    u16* ob = att_t + ((size_t)b * PP * PP + (size_t)(nt + 1) * PP + 1) * C;
#pragma unroll
    for (int j = 0; j < 32; j++) {
        int o = tid + j * 256;
        int c = o & 127, n = o >> 7;
        ob[(size_t)n * C + c] = ts[c * 66 + n];
    }
}

// ---------------------------------------------------------------------------
// 8) Implicit-GEMM MFMA conv3x3 + residual (unchanged, proven).
// ---------------------------------------------------------------------------
__global__ __launch_bounds__(256) void conv3x3_mfma(const u16* __restrict__ att_t,
                                                    const u16* __restrict__ wt,
                                                    const float* __restrict__ bp,
                                                    const float* __restrict__ sr,
                                                    const float* __restrict__ gamma,
                                                    float* __restrict__ out) {
    __shared__ u16 in_s[2][4 * 204 * 8];
    int ib = blockIdx.x;
    int b = (ib & 7) >> 1;
    int y = ((ib >> 3) << 1) | (ib & 1);
    int tid = threadIdx.x;
    int w = tid >> 6, lane = tid & 63, l = tid & 15, quad = (tid >> 4) & 3;
    const u16* ab = att_t + (size_t)b * (PP * PP * C);

    auto stage = [&](int cib, int bufi) {
        u16* base = &in_s[bufi][w * 204 * 8];
        const u16* gsrc = ab + cib * 32 + w * 8;
#pragma unroll
        for (int t = 0; t < 4; t++) {
            int rem = t * 64 + lane;
            int r = rem / 68, xp = rem - r * 68;
            if (t < 3 || lane < 12)
                __builtin_amdgcn_global_load_lds(
                    (const __attribute__((address_space(1))) void*)(gsrc + (size_t)((y + r) * PP + xp) * C),
                    (__attribute__((address_space(3))) void*)(base + (size_t)t * 64 * 8), 16, 0, 0);
        }
    };

    f32x4 acc[2][4];
#pragma unroll
    for (int cf = 0; cf < 2; cf++)
#pragma unroll
        for (int nf = 0; nf < 4; nf++) acc[cf][nf] = (f32x4){0.f, 0.f, 0.f, 0.f};
    int cow = w * 32;

    stage(0, 0);
    __syncthreads();
#pragma unroll
    for (int cib = 0; cib < 4; cib++) {
        if (cib < 3) stage(cib + 1, (cib + 1) & 1);
        const u16* bufc = &in_s[cib & 1][0];
#pragma unroll
        for (int ky = 0; ky < 3; ky++)
#pragma unroll
            for (int kx = 0; kx < 3; kx++) {
                int pos = ky * 3 + kx;
                s16x8 wf[2];
#pragma unroll
                for (int cf = 0; cf < 2; cf++)
                    wf[cf] = *(const s16x8*)&wt[((size_t)(pos * 4 + cib) * C + cow + cf * 16 + l) * 32 + quad * 8];
#pragma unroll
                for (int nf = 0; nf < 4; nf++) {
                    s16x8 inf = *(const s16x8*)&bufc[(quad * 204 + ky * 68 + nf * 16 + l + kx) * 8];
                    acc[0][nf] = __builtin_amdgcn_mfma_f32_16x16x32_bf16(wf[0], inf, acc[0][nf], 0, 0, 0);
                    acc[1][nf] = __builtin_amdgcn_mfma_f32_16x16x32_bf16(wf[1], inf, acc[1][nf], 0, 0, 0);
                }
            }
        __syncthreads();
    }

    float g = gamma[0];
    float* ob = out + (size_t)b * C * NN;
    const float* sb = sr + (size_t)b * C * NN;
#pragma unroll
    for (int cf = 0; cf < 2; cf++)
#pragma unroll
        for (int r = 0; r < 4; r++) {
            int co = cow + cf * 16 + quad * 4 + r;
            float bias = bp[co];
#pragma unroll
            for (int nf = 0; nf < 4; nf++) {
                size_t oo = (size_t)co * NN + y * 64 + nf * 16 + l;
                ob[oo] = sb[oo] + g * (acc[cf][nf][r] + bias);
            }
        }
}

// ---------------------------------------------------------------------------
extern "C" void kernel_launch(void* const* d_in, const int* in_sizes, int n_in,
                              void* d_out, int out_size, void* d_ws, size_t ws_size,
                              hipStream_t stream) {
    const float* sr    = (const float*)d_in[0];
    const float* ctx   = (const float*)d_in[1];
    const float* Wq    = (const float*)d_in[2];
    const float* bq    = (const float*)d_in[3];
    const float* Wk    = (const float*)d_in[4];
    const float* bk    = (const float*)d_in[5];
    const float* Wv    = (const float*)d_in[6];
    const float* bv    = (const float*)d_in[7];
    const float* Wp    = (const float*)d_in[8];
    const float* bp    = (const float*)d_in[9];
    const float* gamma = (const float*)d_in[10];
    float* out = (float*)d_out;

    // ws layout (bytes), ~40 MB total:
    //   att_t bf16 [B][66][66][C]        @0      (4,460,544)
    //   acc f32 [B][C][N] + lacc [B][N]  @5 MB   (8,454,144)
    //   ctx_t bf16 [B][N][CCH]           @14 MB  (8 MB)
    //   sr_t bf16 [B][N][C]              @22 MB  (4 MB)
    //   q_t bf16 [B][N][C]               @26 MB  (4 MB)
    //   k_t bf16 [B][N][C]               @30 MB  (4 MB)
    //   v bf16 [B][C][N]                 @34 MB  (4 MB)
    //   wt bf16 (conv)                   @38 MB  (294,912)
    //   w_bf bf16 (q|k|v)                @38.5MB (163,840)
    char* wsb = (char*)d_ws;
    u16*   att_t  = (u16*)wsb;
    float* acc    = (float*)(wsb + (5u << 20));
    float* lacc   = acc + (size_t)NB * C * NN;
    u16*   ctx_t  = (u16*)(wsb + (14u << 20));
    u16*   sr_t   = (u16*)(wsb + (22u << 20));
    u16*   q_t    = (u16*)(wsb + (26u << 20));
    u16*   k_t    = (u16*)(wsb + (30u << 20));
    u16*   v_bf   = (u16*)(wsb + (34u << 20));
    u16*   wt     = (u16*)(wsb + (38u << 20));
    u16*   w_bf   = (u16*)(wsb + (38u << 20) + (512u << 10));

    upsample_t<<<dim3(64, 2, NB), 256, 0, stream>>>(ctx, ctx_t);
    tcast<<<dim3(64, 2, NB), 256, 0, stream>>>(sr, sr_t, C);
    wprep_all<<<dim3(896), 256, 0, stream>>>(Wq, Wk, Wv, Wp, w_bf, wt);
    zero_all<<<dim3(3153), 256, 0, stream>>>((uint4*)att_t, (uint4*)acc);
    proj_all<<<dim3(32, NB, 3), 256, 0, stream>>>(sr_t, ctx_t, w_bf, bq, bk, bv,
                                                  q_t, k_t, v_bf);
    flash_mfma<<<dim3(1024), 256, 0, stream>>>(q_t, k_t, v_bf, acc, lacc);
    flash_combine<<<dim3(64, NB), 256, 0, stream>>>(acc, lacc, att_t);
    conv3x3_mfma<<<dim3(256), 256, 0, stream>>>(att_t, wt, bp, sr, gamma, out);
}